// Round 5
// baseline (171.592 us; speedup 1.0000x reference)
//
#include <hip/hip_runtime.h>
#include <hip/hip_bf16.h>
#include <math.h>

#define B 8
#define N 2048
#define C 16
#define HID 128
#define NRF 16384      // 128*128
#define MAXLEN 8
#define MAXCH 2048     // max chains per batch (<= N)

// ---------------- setup: init counters + transpose weights + bias ----------
// grid = 512 x 256 = 131072 = B*NRF threads exactly
__global__ __launch_bounds__(256) void k_setup(
    const float* __restrict__ w_ih, const float* __restrict__ w_hh,
    const float* __restrict__ b_ih, const float* __restrict__ b_hh,
    float* __restrict__ w_ih_T, float* __restrict__ w_hh_T,
    float* __restrict__ biassum, int* __restrict__ cntrf,
    int* __restrict__ map, int* __restrict__ cnt) {
    int i = blockIdx.x * blockDim.x + threadIdx.x;
    cntrf[i] = 0;
    map[i] = -1;
    if (i < B) cnt[i] = 0;
    if (i < C * 512) {                 // w_ih_T[c][j] = w_ih[j][c]
        int c = i >> 9, j = i & 511;
        w_ih_T[i] = w_ih[j * C + c];
    }
    if (i < HID * 512) {               // w_hh_T[k][j] = w_hh[j][k]
        int k = i >> 9, j = i & 511;
        w_hh_T[i] = w_hh[j * HID + k];
    }
    if (i < 512) biassum[i] = b_ih[i] + b_hh[i];
}

// ---------------- build: bucket events by (b, rf) ----------------
// R1 lesson: block-aggregated chain registration — ONE device atomic on
// cnt[b] per block (contended same-address atomics cost ~98 ns each).
__global__ __launch_bounds__(256) void k_build(
    const int* __restrict__ coords, int* __restrict__ cntrf,
    int* __restrict__ map, int* __restrict__ cnt,
    int* __restrict__ chainrf, int* __restrict__ slots) {
    int tid = threadIdx.x;
    int idx = blockIdx.x * 256 + tid;   // grid exactly B*N (64 blocks)
    int b = idx >> 11;                  // uniform within block
    int n = idx & (N - 1);
    int x = coords[idx * 2 + 0];
    int y = coords[idx * 2 + 1];
    int rf = y * 128 + x;
    int pos = atomicAdd(&cntrf[b * NRF + rf], 1);
    if (pos < MAXLEN) slots[(b * NRF + rf) * MAXLEN + pos] = n;
    __shared__ int lcnt, lbase;
    if (tid == 0) lcnt = 0;
    __syncthreads();
    int r = -1;
    if (pos == 0) r = atomicAdd(&lcnt, 1);
    __syncthreads();
    if (tid == 0) lbase = atomicAdd(&cnt[b], lcnt);   // 1 per block
    __syncthreads();
    if (pos == 0) {
        int k = lbase + r;
        chainrf[b * MAXCH + k] = rf;
        map[b * NRF + rf] = k;
    }
}

// ---------------- singletons: fused gates + activation -----------------
// Block owns 64 chain slots: cooperative scan -> LDS list -> 4 waves
// process chains. Weights register-cached (96 regs: 6 gate cols x 16,
// f-gate dead since c_prev=0). One 64B feature load + 16 shfl-FMA rounds
// per chain. R4 lesson: no gates_x round-trip (55 MB saved).
__global__ __launch_bounds__(256) void k_single(
    const float* __restrict__ features, const float* __restrict__ w_ih_T,
    const float* __restrict__ biassum, const int* __restrict__ cnt,
    const int* __restrict__ chainrf, const int* __restrict__ cntrf,
    const int* __restrict__ slots, float* __restrict__ hfin) {
    int tid = threadIdx.x;
    int lane = tid & 63, w = tid >> 6;
    __shared__ int l_idx[64], l_ev[64];
    __shared__ int l_n;
    if (tid == 0) l_n = 0;
    __syncthreads();
    if (tid < 64) {                     // parallel slot scan
        int idx = blockIdx.x * 64 + tid;       // grid = 256 blocks
        int b = idx >> 11, j = idx & (MAXCH - 1);
        if (j < cnt[b]) {
            int rf = chainrf[idx];
            int bn = b * NRF + rf;
            if (cntrf[bn] == 1) {
                int r = atomicAdd(&l_n, 1);
                l_idx[r] = idx;
                l_ev[r] = slots[(size_t)bn * MAXLEN];
            }
        }
    }
    __syncthreads();
    int nn = l_n;
    if (nn == 0) return;
    // register-cache the 6 needed gate columns of w_ih_T
    float wi0[16], wi1[16], wg0[16], wg1[16], wo0[16], wo1[16];
#pragma unroll
    for (int c2 = 0; c2 < 16; c2++) {
        wi0[c2] = w_ih_T[c2 * 512 + lane];
        wi1[c2] = w_ih_T[c2 * 512 + lane + 64];
        wg0[c2] = w_ih_T[c2 * 512 + lane + 256];
        wg1[c2] = w_ih_T[c2 * 512 + lane + 320];
        wo0[c2] = w_ih_T[c2 * 512 + lane + 384];
        wo1[c2] = w_ih_T[c2 * 512 + lane + 448];
    }
    float bi0 = biassum[lane],       bi1 = biassum[lane + 64];
    float bg0 = biassum[lane + 256], bg1 = biassum[lane + 320];
    float bo0 = biassum[lane + 384], bo1 = biassum[lane + 448];
    for (int ii = w; ii < nn; ii += 4) {
        int idx = l_idx[ii];
        int n = l_ev[ii];
        int b = idx >> 11;
        float f = 0.f;
        if (lane < 16) f = features[((size_t)(b * N + n)) * C + lane];
        float ai0 = bi0, ai1 = bi1, ag0 = bg0, ag1 = bg1, ao0 = bo0, ao1 = bo1;
#pragma unroll
        for (int c2 = 0; c2 < 16; c2++) {
            float xv = __shfl(f, c2, 64);
            ai0 += wi0[c2] * xv; ai1 += wi1[c2] * xv;
            ag0 += wg0[c2] * xv; ag1 += wg1[c2] * xv;
            ao0 += wo0[c2] * xv; ao1 += wo1[c2] * xv;
        }
        float i0 = 1.f / (1.f + expf(-ai0));
        float i1 = 1.f / (1.f + expf(-ai1));
        float c0 = i0 * tanhf(ag0);
        float c1 = i1 * tanhf(ag1);
        float h0 = (1.f / (1.f + expf(-ao0))) * tanhf(c0);
        float h1 = (1.f / (1.f + expf(-ao1))) * tanhf(c1);
        hfin[(size_t)idx * HID + lane] = h0;
        hfin[(size_t)idx * HID + lane + 64] = h1;
    }
}

// ---------------- multi-event chains: w_hh column in registers -----------
// 512 threads = 512 gate cols; each thread holds its whole w_hh_T column
// (128 VGPRs) + w_ih_T column (16 VGPRs), loaded ONCE per block. Recurrent
// step = 128 register-FMAs with LDS-broadcast h — no per-step L2 traffic
// (R4's version streamed 256 KB of w_hh_T from L2 per step, ~300 MB total).
__global__ __launch_bounds__(512) void k_multi(
    const float* __restrict__ features, const float* __restrict__ w_ih_T,
    const float* __restrict__ w_hh_T, const float* __restrict__ biassum,
    const int* __restrict__ cnt, const int* __restrict__ chainrf,
    const int* __restrict__ cntrf, const int* __restrict__ slots,
    float* __restrict__ hfin) {
    int tid = threadIdx.x;
    __shared__ int l_idx[64];
    __shared__ int l_n;
    __shared__ float g512[512];
    __shared__ float hbuf[HID];
    __shared__ float ls_xs[MAXLEN * 16];
    if (tid == 0) l_n = 0;
    __syncthreads();
    if (tid < 64) {                     // parallel slot scan
        int idx = blockIdx.x * 64 + tid;       // grid = 256 blocks
        int b = idx >> 11, j = idx & (MAXCH - 1);
        if (j < cnt[b]) {
            int rf = chainrf[idx];
            if (cntrf[b * NRF + rf] >= 2) {
                int r = atomicAdd(&l_n, 1);
                l_idx[r] = idx;
            }
        }
    }
    __syncthreads();
    int M = l_n;
    if (M == 0) return;                 // uniform early-exit: skip weight load
    float wh[128];
#pragma unroll
    for (int k = 0; k < 128; k++) wh[k] = w_hh_T[k * 512 + tid];
    float wi[16];
#pragma unroll
    for (int c2 = 0; c2 < 16; c2++) wi[c2] = w_ih_T[c2 * 512 + tid];
    float bb = biassum[tid];
    for (int ii = 0; ii < M; ii++) {
        int idx = l_idx[ii];
        int b = idx >> 11;
        int bn = b * NRF + chainrf[idx];
        int len = cntrf[bn];
        if (len > MAXLEN) len = MAXLEN;
        const int* sl = slots + (size_t)bn * MAXLEN;
        int ev[MAXLEN];
#pragma unroll
        for (int t = 0; t < MAXLEN; t++) {     // static indices -> VGPRs
            int v = sl[t];
            ev[t] = (t < len) ? v : 0x7fffffff;
        }
#pragma unroll
        for (int a = 0; a < MAXLEN; a++)       // sort ascending (time order)
#pragma unroll
            for (int q = 0; q < MAXLEN - 1; q++) {
                int u = ev[q], v = ev[q + 1];
                ev[q] = min(u, v);
                ev[q + 1] = max(u, v);
            }
        // stage all steps' features (static ev[t] indexing)
#pragma unroll
        for (int t = 0; t < MAXLEN; t++)
            if (t < len && tid < 16)
                ls_xs[t * 16 + tid] = features[((size_t)(b * N + ev[t])) * C + tid];
        __syncthreads();
        float c = 0.f;                  // state lives in threads tid < 128
        for (int t = 0; t < len; t++) { // len block-uniform
            float a0 = bb, a1 = 0.f, a2 = 0.f, a3 = 0.f;
#pragma unroll
            for (int c2 = 0; c2 < 16; c2++) a0 += wi[c2] * ls_xs[t * 16 + c2];
            if (t > 0) {
#pragma unroll
                for (int k = 0; k < 128; k += 4) {   // LDS broadcast reads
                    a0 += wh[k] * hbuf[k];
                    a1 += wh[k + 1] * hbuf[k + 1];
                    a2 += wh[k + 2] * hbuf[k + 2];
                    a3 += wh[k + 3] * hbuf[k + 3];
                }
            }
            g512[tid] = (a0 + a1) + (a2 + a3);
            __syncthreads();
            if (tid < HID) {
                float ig = 1.f / (1.f + expf(-g512[tid]));
                float fg = 1.f / (1.f + expf(-g512[tid + 128]));
                float gg = tanhf(g512[tid + 256]);
                float og = 1.f / (1.f + expf(-g512[tid + 384]));
                c = fg * c + ig * gg;
                hbuf[tid] = og * tanhf(c);
            }
            __syncthreads();
        }
        if (tid < HID) hfin[(size_t)idx * HID + tid] = hbuf[tid];
    }
}

// ---------------- scatter to dense [B, HID, 128, 128] ----------------
__global__ __launch_bounds__(256) void k_scatter(
    const float* __restrict__ hfin, const int* __restrict__ map,
    float* __restrict__ out) {
    int b = blockIdx.x >> 7;        // grid = B*128
    int y = blockIdx.x & 127;
    int t = threadIdx.x;
    int xq = t & 31;                // x quad: covers x = 4*xq .. 4*xq+3
    int hg = t >> 5;                // hid group 0..7 (16 hids each)
    const int4* mrow = (const int4*)(map + b * NRF + y * 128);
    int4 kk = mrow[xq];
    const float* hb = hfin + (size_t)b * MAXCH * HID;
#pragma unroll
    for (int hh = 0; hh < 16; hh++) {
        int hid = hg * 16 + hh;
        float4 v;
        v.x = (kk.x < 0) ? 0.f : hb[kk.x * HID + hid];
        v.y = (kk.y < 0) ? 0.f : hb[kk.y * HID + hid];
        v.z = (kk.z < 0) ? 0.f : hb[kk.z * HID + hid];
        v.w = (kk.w < 0) ? 0.f : hb[kk.w * HID + hid];
        *(float4*)(out + ((((size_t)b * HID + hid) * 128 + y) * 128) + xq * 4) = v;
    }
}

extern "C" void kernel_launch(void* const* d_in, const int* in_sizes, int n_in,
                              void* d_out, int out_size, void* d_ws, size_t ws_size,
                              hipStream_t stream) {
    const float* features = (const float*)d_in[0];   // [B,N,C] f32
    const int*   coords   = (const int*)d_in[1];     // [B,N,2] i32
    const float* w_ih     = (const float*)d_in[2];   // [512,16]
    const float* w_hh     = (const float*)d_in[3];   // [512,128]
    const float* b_ih     = (const float*)d_in[4];   // [512]
    const float* b_hh     = (const float*)d_in[5];   // [512]
    float* out = (float*)d_out;                      // [B,128,128,128]

    char* ws = (char*)d_ws;
    float* w_ih_T  = (float*)(ws + 0);               //  32768 B
    float* w_hh_T  = (float*)(ws + 32768);           // 262144 B
    float* biassum = (float*)(ws + 294912);          //   2048 B
    int*   cntrf   = (int*)(ws + 296960);            // 524288 B
    int*   map     = (int*)(ws + 821248);            // 524288 B
    int*   cnt     = (int*)(ws + 1345536);           //     64 B
    int*   chainrf = (int*)(ws + 1345600);           //  65536 B
    int*   slots   = (int*)(ws + 1411136);           // 4194304 B
    float* hfin    = (float*)(ws + 5605440);         // 8388608 B -> ~13.4 MB

    k_setup<<<dim3(B * NRF / 256), dim3(256), 0, stream>>>(
        w_ih, w_hh, b_ih, b_hh, w_ih_T, w_hh_T, biassum, cntrf, map, cnt);
    k_build<<<dim3(B * N / 256), dim3(256), 0, stream>>>(
        coords, cntrf, map, cnt, chainrf, slots);
    k_single<<<dim3(B * MAXCH / 64), dim3(256), 0, stream>>>(
        features, w_ih_T, biassum, cnt, chainrf, cntrf, slots, hfin);
    k_multi<<<dim3(B * MAXCH / 64), dim3(512), 0, stream>>>(
        features, w_ih_T, w_hh_T, biassum, cnt, chainrf, cntrf, slots, hfin);
    k_scatter<<<dim3(B * 128), dim3(256), 0, stream>>>(hfin, map, out);
}